// Round 6
// baseline (43486.484 us; speedup 1.0000x reference)
//
#include <hip/hip_runtime.h>
#include <hip/hip_fp16.h>

// Problem: unbatched GRU scanned over batch-flattened sequence.
//   Encoder: 30720 serial steps, Decoder: 3840 serial steps (independent chains).
//   Per step: gh = W_hh (768x256) . h (256)  -- serial in h.
// History:
//   R1: 768thr, 128 weight regs vs 84 budget -> remat from global, 27GB, 36.7ms.
//   R2: launch_bounds(768,3): no-op. R3/R4: dynamic-index bug -> scratch, 334ms.
//   R5: LDS>80KB forced 1 blk/CU but VGPR budget settled at 128 (4 w/EU);
//       demand was 192 -> overflow refetched, 27GB again, 36.4ms.
//   Rule learned: demand must FIT the occupancy-derived budget.
//   Also: streaming weights (L2 or LDS) floors at ~3000 cyc/step == 36ms;
//   only register residency reaches the 768-cyc dot2 floor.
// R6: 1024 threads (16 waves, VGPR cap 128). Per-thread weights = 192 f16
//   = 96 regs < 128. thread=(rg=tid>>2, q=tid&3): rows {rg, rg+256, rg+512}
//   (r/z/n of unit rg) x cols [64q,64q+64). Quad butterfly shfl_xor(1,2)
//   combines quarters; q==0 writes gh. Weights laundered through LDS
//   (cross-thread stagger; all indices compile-time constant -> SSA).
//   b_hh(r,z) folded into K1 bias; b_hh(n) added at gh write.

typedef _Float16 h2 __attribute__((ext_vector_type(2)));
typedef _Float16 h4 __attribute__((ext_vector_type(4)));

union HU { unsigned int u; h2 v; };

__device__ __forceinline__ h2 as_h2(unsigned int u) { HU x; x.u = u; return x.v; }

__device__ __forceinline__ float fdot2(h2 a, h2 b, float c) {
#if __has_builtin(__builtin_amdgcn_fdot2)
  return __builtin_amdgcn_fdot2(a, b, c, false);
#else
  return c + (float)a[0] * (float)b[0] + (float)a[1] * (float)b[1];
#endif
}

__device__ __forceinline__ float fast_sigmoid(float x) {
  return __builtin_amdgcn_rcpf(1.0f + __builtin_amdgcn_exp2f(x * -1.4426950408889634f));
}

constexpr int B = 128, T_IN = 240, T_OUT = 30, D = 128, H = 256, G = 768; // G = 3H
constexpr int L_ENC = B * T_IN;   // 30720
constexpr int L_DEC = B * T_OUT;  // 3840
// workspace need: (L_ENC + L_DEC) * G * sizeof(_Float16) = 53,084,160 bytes

// ---------------- K1: gi = x @ W_ih^T + (b_ih [+ b_hh for r,z cols]) --------
__global__ __launch_bounds__(256) void gi_gemm(
    const float* __restrict__ x,
    const float* __restrict__ Wih_e, const float* __restrict__ bih_e,
    const float* __restrict__ bhh_e,
    const float* __restrict__ Wih_d, const float* __restrict__ bih_d,
    const float* __restrict__ bhh_d,
    _Float16* __restrict__ gi)
{
  const int jt = blockIdx.x;            // 0..11
  const int by = blockIdx.y;            // 0..539
  const bool enc = by < (L_ENC / 64);
  const int row0 = enc ? by * 64 : (by - L_ENC / 64) * 64;  // segment-local
  const float* __restrict__ W  = enc ? Wih_e : Wih_d;
  const float* __restrict__ bi = enc ? bih_e : bih_d;
  const float* __restrict__ bh = enc ? bhh_e : bhh_d;
  _Float16* __restrict__ gout = enc ? gi : gi + (size_t)L_ENC * G;

  __shared__ float xs[64][132];   // +4 pad
  __shared__ float ws[64][132];
  const int t = threadIdx.x;
#pragma unroll
  for (int p = 0; p < 8; ++p) {
    int idx = p * 256 + t;
    int r  = idx >> 5;
    int c4 = (idx & 31) * 4;
    int i  = row0 + r;
    int bb = i & (B - 1);
    int tt = i >> 7;
    if (!enc) tt *= 8;            // decoder reads x[:, ::8, :]
    float4 xv = *(const float4*)(x + (size_t)(bb * T_IN + tt) * D + c4);
    *(float4*)&xs[r][c4] = xv;
    float4 wv = *(const float4*)(W + (size_t)(jt * 64 + r) * D + c4);
    *(float4*)&ws[r][c4] = wv;
  }
  __syncthreads();

  const int tr = t >> 4, tc = t & 15;
  float acc[4][4] = {};
  for (int k4 = 0; k4 < 128; k4 += 4) {
    float4 xa[4], wa[4];
#pragma unroll
    for (int q = 0; q < 4; ++q) xa[q] = *(const float4*)&xs[tr * 4 + q][k4];
#pragma unroll
    for (int q = 0; q < 4; ++q) wa[q] = *(const float4*)&ws[tc * 4 + q][k4];
#pragma unroll
    for (int r = 0; r < 4; ++r)
#pragma unroll
      for (int c = 0; c < 4; ++c)
        acc[r][c] += xa[r].x * wa[c].x + xa[r].y * wa[c].y +
                     xa[r].z * wa[c].z + xa[r].w * wa[c].w;
  }

  const int col = jt * 64 + tc * 4;
  float bv[4];
#pragma unroll
  for (int c = 0; c < 4; ++c) {
    bv[c] = bi[col + c];
    if (col + c < 2 * H) bv[c] += bh[col + c];   // fold b_hh for r,z gates
  }
#pragma unroll
  for (int r = 0; r < 4; ++r) {
    int grow = row0 + tr * 4 + r;
    h4 o;
#pragma unroll
    for (int c = 0; c < 4; ++c) o[c] = (_Float16)(acc[r][c] + bv[c]);
    *(h4*)(gout + (size_t)grow * G + col) = o;
  }
}

// ---------------- K2: serial GRU scan --------------------------------------
// block 0 = encoder, block 1 = decoder. 1024 threads = 16 waves, 1 block/CU.
constexpr int NT = 1024;
constexpr int NQ = 24;               // uint4 weights per thread (96 VGPRs)
constexpr int CHUNK = 6;             // uint4 per thread per staging round
// stage LDS = 1024*6*16 = 98304 B > 80KB -> 1 block/CU (structural).

__global__
__attribute__((amdgpu_flat_work_group_size(NT, NT)))
__attribute__((amdgpu_waves_per_eu(4, 4)))
void gru_serial(
    const _Float16* __restrict__ gi,
    const float* __restrict__ Whh_e, const float* __restrict__ bhh_e,
    const float* __restrict__ Whh_d, const float* __restrict__ bhh_d,
    float* __restrict__ out)
{
  const int tid = threadIdx.x;
  const bool enc = (blockIdx.x == 0);
  const int L = enc ? L_ENC : L_DEC;
  const float* __restrict__ W  = enc ? Whh_e : Whh_d;
  const float* __restrict__ bh = enc ? bhh_e : bhh_d;
  const _Float16* __restrict__ gbase = enc ? gi : gi + (size_t)L_ENC * G;
  float* __restrict__ obase = enc ? out : out + T_IN * H;

  __shared__ __align__(16) uint4 stage_q[NT * CHUNK];   // 98304 B
  __shared__ __align__(16) unsigned int h_lds[H / 2];   // 256 f16 as 128 uints
  __shared__ float gh_lds[G];                            // W_hh.h (+b_hh_n) rows

  const int rg = tid >> 2;    // unit 0..255 (owns r/z/n rows of this unit)
  const int q  = tid & 3;     // column quarter

  // ---- Stage weights via LDS bounce; thread t loads for t'=(t+1)&1023. ----
  // wq[u]: u = m*8 + ci, m=row(0..2: r,z,n), ci=16B chunk in 64-col quarter.
  uint4 wq[NQ];
  {
    const int tp  = (tid + 1) & (NT - 1);
    const int rgp = tp >> 2, qp = tp & 3;
#pragma unroll
    for (int cch = 0; cch < 4; ++cch) {
#pragma unroll
      for (int j = 0; j < CHUNK; ++j) {
        const int u  = cch * CHUNK + j;     // 0..23, compile-time constant
        const int m  = u >> 3;              // 0..2
        const int ci = u & 7;               // 0..7
        const float* p = W + (size_t)(rgp + m * H) * H + qp * 64 + ci * 8;
        float4 f0 = *(const float4*)(p);
        float4 f1 = *(const float4*)(p + 4);
        HU a, b, c2, d;
        a.v[0]  = (_Float16)f0.x; a.v[1]  = (_Float16)f0.y;
        b.v[0]  = (_Float16)f0.z; b.v[1]  = (_Float16)f0.w;
        c2.v[0] = (_Float16)f1.x; c2.v[1] = (_Float16)f1.y;
        d.v[0]  = (_Float16)f1.z; d.v[1]  = (_Float16)f1.w;
        uint4 pk; pk.x = a.u; pk.y = b.u; pk.z = c2.u; pk.w = d.u;
        stage_q[tp * CHUNK + j] = pk;
      }
      __syncthreads();
#pragma unroll
      for (int j = 0; j < CHUNK; ++j)
        wq[cch * CHUNK + j] = stage_q[tid * CHUNK + j];
      __syncthreads();
    }
  }

  const float b_n = bh[2 * H + rg];   // n-row bias (used by q==0 at gh write)

  if (tid < H / 2) h_lds[tid] = 0u;   // h0 = 0
  float h_old = 0.0f;                 // gate threads' f32 h[tid]
  __syncthreads();

  // Gate threads (tid<256) prefetch gi for step 0 (r,z have b_hh folded in K1).
  float g0n = 0.f, g1n = 0.f, g2n = 0.f;
  if (tid < H) {
    g0n = (float)gbase[tid];
    g1n = (float)gbase[H + tid];
    g2n = (float)gbase[2 * H + tid];
  }

  for (int i = 0; i < L; ++i) {
    // ---- matvec: 3 rows x 64-col quarter per thread --------------------
    float s0 = 0.f, t0 = 0.f, s1 = 0.f, t1 = 0.f, s2 = 0.f, t2 = 0.f;
    const uint4* hp = (const uint4*)h_lds;
#pragma unroll
    for (int c = 0; c < 8; ++c) {
      uint4 hv = hp[q * 8 + c];       // 4 distinct addrs/wave: broadcast-cheap
      s0 = fdot2(as_h2(wq[c].x),      as_h2(hv.x), s0);
      t0 = fdot2(as_h2(wq[c].y),      as_h2(hv.y), t0);
      s0 = fdot2(as_h2(wq[c].z),      as_h2(hv.z), s0);
      t0 = fdot2(as_h2(wq[c].w),      as_h2(hv.w), t0);
      s1 = fdot2(as_h2(wq[8 + c].x),  as_h2(hv.x), s1);
      t1 = fdot2(as_h2(wq[8 + c].y),  as_h2(hv.y), t1);
      s1 = fdot2(as_h2(wq[8 + c].z),  as_h2(hv.z), s1);
      t1 = fdot2(as_h2(wq[8 + c].w),  as_h2(hv.w), t1);
      s2 = fdot2(as_h2(wq[16 + c].x), as_h2(hv.x), s2);
      t2 = fdot2(as_h2(wq[16 + c].y), as_h2(hv.y), t2);
      s2 = fdot2(as_h2(wq[16 + c].z), as_h2(hv.z), s2);
      t2 = fdot2(as_h2(wq[16 + c].w), as_h2(hv.w), t2);
    }
    float r0 = s0 + t0, r1 = s1 + t1, r2 = s2 + t2;
    // combine 4 column-quarters within the lane quad
    r0 += __shfl_xor(r0, 1); r0 += __shfl_xor(r0, 2);
    r1 += __shfl_xor(r1, 1); r1 += __shfl_xor(r1, 2);
    r2 += __shfl_xor(r2, 1); r2 += __shfl_xor(r2, 2);
    if (q == 0) {
      gh_lds[rg]         = r0;         // r-row (b_hh folded into gi via K1)
      gh_lds[H + rg]     = r1;         // z-row
      gh_lds[2 * H + rg] = r2 + b_n;   // n-row needs b_hh before r-multiply
    }
    __syncthreads();

    // ---- gates (tid < 256 = waves 0..3) --------------------------------
    if (tid < H) {
      const float gc0 = g0n, gc1 = g1n, gc2 = g2n;
      {
        const size_t nb = (size_t)((i + 1 < L) ? i + 1 : i) * G;
        g0n = (float)gbase[nb + tid];           // prefetch next step's gi
        g1n = (float)gbase[nb + H + tid];
        g2n = (float)gbase[nb + 2 * H + tid];
      }
      const float pr = gh_lds[tid] + gc0;
      const float pz = gh_lds[H + tid] + gc1;
      const float hn = gh_lds[2 * H + tid];
      const float r = fast_sigmoid(pr);
      const float z = fast_sigmoid(pz);
      const float n = 2.0f * fast_sigmoid(2.0f * (gc2 + r * hn)) - 1.0f; // tanh
      const float hnew = (1.0f - z) * n + z * h_old;
      h_old = hnew;
      ((_Float16*)h_lds)[tid] = (_Float16)hnew;
      if (enc) {
        if ((i & (B - 1)) == (B - 1))           // every 128th step
          obase[(i >> 7) * H + tid] = hnew;
      } else {
        obase[((i & (B - 1)) * T_OUT + (i >> 7)) * H + tid] = hnew;
      }
    }
    __syncthreads();
  }
}

extern "C" void kernel_launch(void* const* d_in, const int* in_sizes, int n_in,
                              void* d_out, int out_size, void* d_ws, size_t ws_size,
                              hipStream_t stream) {
  (void)in_sizes; (void)n_in; (void)out_size; (void)ws_size;
  const float* x     = (const float*)d_in[0];
  const float* Wih_e = (const float*)d_in[1];
  const float* Whh_e = (const float*)d_in[2];
  const float* bih_e = (const float*)d_in[3];
  const float* bhh_e = (const float*)d_in[4];
  const float* Wih_d = (const float*)d_in[5];
  const float* Whh_d = (const float*)d_in[6];
  const float* bih_d = (const float*)d_in[7];
  const float* bhh_d = (const float*)d_in[8];
  float* out = (float*)d_out;
  _Float16* gi = (_Float16*)d_ws;    // needs 53,084,160 B

  dim3 g1(12, (L_ENC + L_DEC) / 64);
  gi_gemm<<<g1, 256, 0, stream>>>(x, Wih_e, bih_e, bhh_e, Wih_d, bih_d, bhh_d, gi);
  gru_serial<<<dim3(2), dim3(1024), 0, stream>>>(gi, Whh_e, bhh_e, Whh_d, bhh_d, out);
}

// Round 8
// 42110.938 us; speedup vs baseline: 1.0327x; 1.0327x over previous
//
#include <hip/hip_runtime.h>
#include <hip/hip_fp16.h>

// Problem: unbatched GRU over batch-flattened sequence. Encoder 30720 serial
// steps, decoder 3840 (independent). Per step: gh = W_hh(768x256) . h(256).
// History: R1-R6 -- compiler-managed residency of W_hh (393KB = 77% of the
//   512KB/CU register file) always fails: allocator budgets ~50% of file and
//   sheds weights to per-step global refetch (FETCH 27GB, ~2850 cyc/step).
//   R7: AGPR pinning compiled, but v_dot2 can't read AGPRs (VOP3P restriction).
// R8: consumers must be MFMA (only class that sources AGPRs). Matvec as
//   768x256x1 GEMM via v_mfma_f32_16x16x32_f16: 48 row-tiles x 8 K-tiles,
//   8 waves x 6 tiles, K chained through C. A-fragments (W_hh f16) pinned in
//   a0..a191 by one-time v_accvgpr_write; referenced only inside volatile asm
//   so the allocator never sees them. B = h replicated across columns: one
//   quad-broadcast ds_read_b128 per K-tile per lane. D col 0 extracted by
//   lanes (lane&15)==0 as ds_write_b128. s_nop guards MFMA->mem hazards
//   (inline asm = compiler won't add them). 512 thr, waves_per_eu(2,2):
//   8 waves x (192a + <=64v) = full file, 1 block/CU.

typedef _Float16 h2 __attribute__((ext_vector_type(2)));
typedef _Float16 h4 __attribute__((ext_vector_type(4)));
typedef float f32x4 __attribute__((ext_vector_type(4)));
typedef unsigned int uv4 __attribute__((ext_vector_type(4)));

union HU { unsigned int u; h2 v; };

__device__ __forceinline__ float fast_sigmoid(float x) {
  return __builtin_amdgcn_rcpf(1.0f + __builtin_amdgcn_exp2f(x * -1.4426950408889634f));
}

__device__ __forceinline__ uint4 pack8(const float* p) {
  float4 f0 = *(const float4*)p;
  float4 f1 = *(const float4*)(p + 4);
  HU a, b, c, d;
  a.v[0] = (_Float16)f0.x; a.v[1] = (_Float16)f0.y;
  b.v[0] = (_Float16)f0.z; b.v[1] = (_Float16)f0.w;
  c.v[0] = (_Float16)f1.x; c.v[1] = (_Float16)f1.y;
  d.v[0] = (_Float16)f1.z; d.v[1] = (_Float16)f1.w;
  return make_uint4(a.u, b.u, c.u, d.u);
}

constexpr int B = 128, T_IN = 240, T_OUT = 30, D = 128, H = 256, G = 768; // G=3H
constexpr int L_ENC = B * T_IN;   // 30720
constexpr int L_DEC = B * T_OUT;  // 3840
// workspace: (L_ENC + L_DEC) * G * sizeof(_Float16) = 53,084,160 bytes

// ---------------- K1: gi = x @ W_ih^T + (b_ih [+ b_hh for r,z cols]) --------
__global__ __launch_bounds__(256) void gi_gemm(
    const float* __restrict__ x,
    const float* __restrict__ Wih_e, const float* __restrict__ bih_e,
    const float* __restrict__ bhh_e,
    const float* __restrict__ Wih_d, const float* __restrict__ bih_d,
    const float* __restrict__ bhh_d,
    _Float16* __restrict__ gi)
{
  const int jt = blockIdx.x;            // 0..11
  const int by = blockIdx.y;            // 0..539
  const bool enc = by < (L_ENC / 64);
  const int row0 = enc ? by * 64 : (by - L_ENC / 64) * 64;
  const float* __restrict__ W  = enc ? Wih_e : Wih_d;
  const float* __restrict__ bi = enc ? bih_e : bih_d;
  const float* __restrict__ bh = enc ? bhh_e : bhh_d;
  _Float16* __restrict__ gout = enc ? gi : gi + (size_t)L_ENC * G;

  __shared__ float xs[64][132];   // +4 pad
  __shared__ float ws[64][132];
  const int t = threadIdx.x;
#pragma unroll
  for (int p = 0; p < 8; ++p) {
    int idx = p * 256 + t;
    int r  = idx >> 5;
    int c4 = (idx & 31) * 4;
    int i  = row0 + r;
    int bb = i & (B - 1);
    int tt = i >> 7;
    if (!enc) tt *= 8;            // decoder reads x[:, ::8, :]
    float4 xv = *(const float4*)(x + (size_t)(bb * T_IN + tt) * D + c4);
    *(float4*)&xs[r][c4] = xv;
    float4 wv = *(const float4*)(W + (size_t)(jt * 64 + r) * D + c4);
    *(float4*)&ws[r][c4] = wv;
  }
  __syncthreads();

  const int tr = t >> 4, tc = t & 15;
  float acc[4][4] = {};
  for (int k4 = 0; k4 < 128; k4 += 4) {
    float4 xa[4], wa[4];
#pragma unroll
    for (int q = 0; q < 4; ++q) xa[q] = *(const float4*)&xs[tr * 4 + q][k4];
#pragma unroll
    for (int q = 0; q < 4; ++q) wa[q] = *(const float4*)&ws[tc * 4 + q][k4];
#pragma unroll
    for (int r = 0; r < 4; ++r)
#pragma unroll
      for (int c = 0; c < 4; ++c)
        acc[r][c] += xa[r].x * wa[c].x + xa[r].y * wa[c].y +
                     xa[r].z * wa[c].z + xa[r].w * wa[c].w;
  }

  const int col = jt * 64 + tc * 4;
  float bv[4];
#pragma unroll
  for (int c = 0; c < 4; ++c) {
    bv[c] = bi[col + c];
    if (col + c < 2 * H) bv[c] += bh[col + c];   // fold b_hh for r,z gates
  }
#pragma unroll
  for (int r = 0; r < 4; ++r) {
    int grow = row0 + tr * 4 + r;
    h4 o;
#pragma unroll
    for (int c = 0; c < 4; ++c) o[c] = (_Float16)(acc[r][c] + bv[c]);
    *(h4*)(gout + (size_t)grow * G + col) = o;
  }
}

// ---------------- K2: serial GRU scan, W_hh as MFMA A-fragments in AGPRs ----
#define AW(N, V) asm volatile("v_accvgpr_write_b32 a" #N ", %0" :: "v"(V) : "a" #N)
#define AW4(N0, N1, N2, N3, Q) do { uint4 _q = (Q); \
  AW(N0, _q.x); AW(N1, _q.y); AW(N2, _q.z); AW(N3, _q.w); } while (0)
#define LF(T, KT, N0, N1, N2, N3) \
  AW4(N0, N1, N2, N3, pack8(pw + (T) * 4096 + (KT) * 32))

#define MFMA_(N0, N3, ACC, BF) \
  asm volatile("v_mfma_f32_16x16x32_f16 %0, a[" #N0 ":" #N3 "], %1, %0" \
               : "+v"(ACC) : "v"(BF))

#define KBLK(KT, A0,A3, B0,B3, C0,C3, D0,D3, E0,E3, F0,F3) do { \
  uv4 bb = hp[(KT) * 4 + q]; \
  MFMA_(A0, A3, c0, bb); MFMA_(B0, B3, c1, bb); MFMA_(C0, C3, c2, bb); \
  MFMA_(D0, D3, c3, bb); MFMA_(E0, E3, c4, bb); MFMA_(F0, F3, c5, bb); } while (0)

__global__
__attribute__((amdgpu_flat_work_group_size(512, 512)))
__attribute__((amdgpu_waves_per_eu(2, 2)))
void gru_serial(
    const _Float16* __restrict__ gi,
    const float* __restrict__ Whh_e, const float* __restrict__ bhh_e,
    const float* __restrict__ Whh_d, const float* __restrict__ bhh_d,
    float* __restrict__ out)
{
  const int tid = threadIdx.x;
  const bool enc = (blockIdx.x == 0);
  const int L = enc ? L_ENC : L_DEC;
  const float* __restrict__ W  = enc ? Whh_e : Whh_d;
  const float* __restrict__ bh = enc ? bhh_e : bhh_d;
  const _Float16* __restrict__ gbase = enc ? gi : gi + (size_t)L_ENC * G;
  float* __restrict__ obase = enc ? out : out + T_IN * H;

  __shared__ __align__(16) unsigned int h_lds[H / 2]; // 256 f16 as 128 uints
  __shared__ __align__(16) float gh_lds[G];           // raw W_hh.h, row-indexed

  const int lane = tid & 63, wave = tid >> 6;
  const int q = lane >> 4;            // quad 0..3

  // ---- One-time: 6 row-tiles x 8 K-tiles of A-fragments -> a0..a191. ------
  // Fragment (t,kt) at a[t*32+kt*4 .. +3]; lane holds
  // A[m = lane&15][k = q*8 + j], i.e. 16B of W row (wave*96 + t*16 + (lane&15))
  // at col kt*32 + q*8.
  {
    const float* pw = W + (size_t)(wave * 96 + (lane & 15)) * H + q * 8;
    LF(0,0,   0,  1,  2,  3); LF(0,1,   4,  5,  6,  7);
    LF(0,2,   8,  9, 10, 11); LF(0,3,  12, 13, 14, 15);
    LF(0,4,  16, 17, 18, 19); LF(0,5,  20, 21, 22, 23);
    LF(0,6,  24, 25, 26, 27); LF(0,7,  28, 29, 30, 31);
    LF(1,0,  32, 33, 34, 35); LF(1,1,  36, 37, 38, 39);
    LF(1,2,  40, 41, 42, 43); LF(1,3,  44, 45, 46, 47);
    LF(1,4,  48, 49, 50, 51); LF(1,5,  52, 53, 54, 55);
    LF(1,6,  56, 57, 58, 59); LF(1,7,  60, 61, 62, 63);
    LF(2,0,  64, 65, 66, 67); LF(2,1,  68, 69, 70, 71);
    LF(2,2,  72, 73, 74, 75); LF(2,3,  76, 77, 78, 79);
    LF(2,4,  80, 81, 82, 83); LF(2,5,  84, 85, 86, 87);
    LF(2,6,  88, 89, 90, 91); LF(2,7,  92, 93, 94, 95);
    LF(3,0,  96, 97, 98, 99); LF(3,1, 100,101,102,103);
    LF(3,2, 104,105,106,107); LF(3,3, 108,109,110,111);
    LF(3,4, 112,113,114,115); LF(3,5, 116,117,118,119);
    LF(3,6, 120,121,122,123); LF(3,7, 124,125,126,127);
    LF(4,0, 128,129,130,131); LF(4,1, 132,133,134,135);
    LF(4,2, 136,137,138,139); LF(4,3, 140,141,142,143);
    LF(4,4, 144,145,146,147); LF(4,5, 148,149,150,151);
    LF(4,6, 152,153,154,155); LF(4,7, 156,157,158,159);
    LF(5,0, 160,161,162,163); LF(5,1, 164,165,166,167);
    LF(5,2, 168,169,170,171); LF(5,3, 172,173,174,175);
    LF(5,4, 176,177,178,179); LF(5,5, 180,181,182,183);
    LF(5,6, 184,185,186,187); LF(5,7, 188,189,190,191);
  }

  if (tid < H / 2) h_lds[tid] = 0u;   // h0 = 0
  float h_old = 0.0f;                 // gate threads' f32 h[tid]
  float bnn = 0.0f;                   // b_hh for n-gate, added in gate phase
  if (tid < H) bnn = bh[2 * H + tid];
  __syncthreads();

  // Gate threads (tid<256) prefetch gi for step 0 (r,z biases folded in K1).
  float g0n = 0.f, g1n = 0.f, g2n = 0.f;
  if (tid < H) {
    g0n = (float)gbase[tid];
    g1n = (float)gbase[H + tid];
    g2n = (float)gbase[2 * H + tid];
  }

  const uv4* hp = (const uv4*)h_lds;  // B-fragment source: hp[kt*4 + q]

  for (int i = 0; i < L; ++i) {
    // ---- matvec via MFMA: 6 chained accumulators over 8 K-tiles ----------
    f32x4 c0 = {0.f,0.f,0.f,0.f}, c1 = {0.f,0.f,0.f,0.f}, c2 = {0.f,0.f,0.f,0.f};
    f32x4 c3 = {0.f,0.f,0.f,0.f}, c4 = {0.f,0.f,0.f,0.f}, c5 = {0.f,0.f,0.f,0.f};
    KBLK(0,   0,  3,  32, 35,  64, 67,  96, 99, 128,131, 160,163);
    KBLK(1,   4,  7,  36, 39,  68, 71, 100,103, 132,135, 164,167);
    KBLK(2,   8, 11,  40, 43,  72, 75, 104,107, 136,139, 168,171);
    KBLK(3,  12, 15,  44, 47,  76, 79, 108,111, 140,143, 172,175);
    KBLK(4,  16, 19,  48, 51,  80, 83, 112,115, 144,147, 176,179);
    KBLK(5,  20, 23,  52, 55,  84, 87, 116,119, 148,151, 180,183);
    KBLK(6,  24, 27,  56, 59,  88, 91, 120,123, 152,155, 184,187);
    KBLK(7,  28, 31,  60, 63,  92, 95, 124,127, 156,159, 188,191);
    asm volatile("s_nop 7\n\ts_nop 7");   // MFMA -> mem-read hazard guard
    // D col 0 lives in lanes lane&15==0: rows = wave*96 + t*16 + q*4 + reg.
    if ((lane & 15) == 0) {
      const int wb = wave * 96 + q * 4;
      *(f32x4*)&gh_lds[wb +  0] = c0;
      *(f32x4*)&gh_lds[wb + 16] = c1;
      *(f32x4*)&gh_lds[wb + 32] = c2;
      *(f32x4*)&gh_lds[wb + 48] = c3;
      *(f32x4*)&gh_lds[wb + 64] = c4;
      *(f32x4*)&gh_lds[wb + 80] = c5;
    }
    __syncthreads();

    // ---- gates (tid < 256) ----------------------------------------------
    if (tid < H) {
      const float gc0 = g0n, gc1 = g1n, gc2 = g2n;
      {
        const size_t nb = (size_t)((i + 1 < L) ? i + 1 : i) * G;
        g0n = (float)gbase[nb + tid];           // prefetch next step's gi
        g1n = (float)gbase[nb + H + tid];
        g2n = (float)gbase[nb + 2 * H + tid];
      }
      const float pr = gh_lds[tid] + gc0;
      const float pz = gh_lds[H + tid] + gc1;
      const float hn = gh_lds[2 * H + tid] + bnn;
      const float r = fast_sigmoid(pr);
      const float z = fast_sigmoid(pz);
      const float n = 2.0f * fast_sigmoid(2.0f * (gc2 + r * hn)) - 1.0f; // tanh
      const float hnew = (1.0f - z) * n + z * h_old;
      h_old = hnew;
      ((_Float16*)h_lds)[tid] = (_Float16)hnew;
      if (enc) {
        if ((i & (B - 1)) == (B - 1))           // every 128th step
          obase[(i >> 7) * H + tid] = hnew;
      } else {
        obase[((i & (B - 1)) * T_OUT + (i >> 7)) * H + tid] = hnew;
      }
    }
    __syncthreads();
  }
}

extern "C" void kernel_launch(void* const* d_in, const int* in_sizes, int n_in,
                              void* d_out, int out_size, void* d_ws, size_t ws_size,
                              hipStream_t stream) {
  (void)in_sizes; (void)n_in; (void)out_size; (void)ws_size;
  const float* x     = (const float*)d_in[0];
  const float* Wih_e = (const float*)d_in[1];
  const float* Whh_e = (const float*)d_in[2];
  const float* bih_e = (const float*)d_in[3];
  const float* bhh_e = (const float*)d_in[4];
  const float* Wih_d = (const float*)d_in[5];
  const float* Whh_d = (const float*)d_in[6];
  const float* bih_d = (const float*)d_in[7];
  const float* bhh_d = (const float*)d_in[8];
  float* out = (float*)d_out;
  _Float16* gi = (_Float16*)d_ws;    // needs 53,084,160 B

  dim3 g1(12, (L_ENC + L_DEC) / 64);
  gi_gemm<<<g1, 256, 0, stream>>>(x, Wih_e, bih_e, bhh_e, Wih_d, bih_d, bhh_d, gi);
  gru_serial<<<dim3(2), dim3(512), 0, stream>>>(gi, Whh_e, bhh_e, Whh_d, bhh_d, out);
}